// Round 4
// baseline (1190.551 us; speedup 1.0000x reference)
//
#include <hip/hip_runtime.h>
#include <math.h>

// RelationMessagePassing — bf16 MFMA + counting-sort scatter (atomic-free reduce).
//
// Round-3 finding: 121.6M fp32 atomicAdds ran at ~102 G/s and were ~90% of
// runtime (MfmaUtil 0.8%, VALUBusy 6%, HBM 5% on rel kernels). This round
// replaces the scatter with: histogram (int atomics) -> exclusive scan ->
// CSR-slot message write (fp16 exp(8*o), streaming) -> per-node wave reduce.
//
//   0. memset: gmax + hist
//   1. conv_states (f32->bf16), transpose_w (8 mats -> bf16 [n][k])
//   2. hist_k x3: hist[node] += 1 over 1.9M participant indices
//   3. scanA/scanB/scanC: nodeStart = exclusive scan(hist); cursor = copy
//   4. rel_mfma<64/128/192>: gather -> MFMA MLP -> atomicMax(gmax)
//      + msgbuf[atomicAdd(cursor[node],1)*64+f] = fp16(exp(8*o_f))
//   5. reduce_k: exps[n][f] = sum fp32 over segment (deg-0 -> 0)
//   6. up_mfma: max_msg = log(1e-16+S*e^-8M)/8+M; concat; MFMA; store fp32
//
// Fallback: if ws_size can't hold msgbuf (~285 MB total), use round-3 atomic path.

typedef __attribute__((ext_vector_type(8))) short bf16x8;
typedef __attribute__((ext_vector_type(4))) float f32x4;
typedef unsigned short u16;

__device__ __forceinline__ unsigned f2ord(float f) {
    unsigned u = __float_as_uint(f);
    return (u & 0x80000000u) ? ~u : (u | 0x80000000u);
}
__device__ __forceinline__ float ord2f(unsigned u) {
    return (u & 0x80000000u) ? __uint_as_float(u & 0x7fffffffu) : __uint_as_float(~u);
}
__device__ __forceinline__ u16 f2bf(float f) {
    unsigned u = __float_as_uint(f);
    return (u16)((u + 0x7fffu + ((u >> 16) & 1u)) >> 16);
}

// ---------------- prep ----------------
__global__ __launch_bounds__(256) void conv_states(const float* __restrict__ src,
                                                   u16* __restrict__ dst, int n8) {
    int i = blockIdx.x * 256 + threadIdx.x;
    if (i >= n8) return;
    float4 a = reinterpret_cast<const float4*>(src)[2 * i];
    float4 b = reinterpret_cast<const float4*>(src)[2 * i + 1];
    bf16x8 v;
    v[0] = (short)f2bf(a.x); v[1] = (short)f2bf(a.y);
    v[2] = (short)f2bf(a.z); v[3] = (short)f2bf(a.w);
    v[4] = (short)f2bf(b.x); v[5] = (short)f2bf(b.y);
    v[6] = (short)f2bf(b.z); v[7] = (short)f2bf(b.w);
    reinterpret_cast<bf16x8*>(dst)[i] = v;
}

struct TEnt { const float* src; u16* dst; int K, N, base; };
struct TPack { TEnt e[8]; };
__global__ __launch_bounds__(256) void transpose_w(TPack p) {
    int b = blockIdx.x;
    int i = 0;
    while (i < 7 && b >= p.e[i + 1].base) ++i;
    TEnt e = p.e[i];
    int idx = (b - e.base) * 256 + threadIdx.x;
    if (idx < e.K * e.N) {
        int n = idx / e.K, k = idx - n * e.K;
        e.dst[idx] = f2bf(e.src[k * e.N + n]);
    }
}

// ---------------- sort machinery ----------------
__global__ __launch_bounds__(256) void hist_k(const int* __restrict__ idx, int n,
                                              int* __restrict__ hist) {
    int i = blockIdx.x * 256 + threadIdx.x;
    if (i < n) atomicAdd(&hist[idx[i]], 1);
}

// chunk=1024 per block
__global__ __launch_bounds__(256) void scanA(const int* __restrict__ hist, int N,
                                             int* __restrict__ partial) {
    __shared__ int ts[256];
    int b = blockIdx.x, t = threadIdx.x;
    int i0 = b * 1024 + t * 4;
    int s = 0;
    #pragma unroll
    for (int q = 0; q < 4; ++q) s += (i0 + q < N) ? hist[i0 + q] : 0;
    ts[t] = s;
    __syncthreads();
    for (int off = 128; off; off >>= 1) {
        if (t < off) ts[t] += ts[t + off];
        __syncthreads();
    }
    if (t == 0) partial[b] = ts[0];
}

__global__ __launch_bounds__(64) void scanB(int* __restrict__ partial, int B1) {
    if (threadIdx.x == 0) {
        int run = 0;
        for (int i = 0; i < B1; ++i) { int t = partial[i]; partial[i] = run; run += t; }
    }
}

__global__ __launch_bounds__(256) void scanC(const int* __restrict__ hist, int N,
                                             const int* __restrict__ partial,
                                             int* __restrict__ nodeStart,
                                             int* __restrict__ cursor) {
    __shared__ int ts[256];
    int b = blockIdx.x, t = threadIdx.x;
    int i0 = b * 1024 + t * 4;
    int v[4];
    int s = 0;
    #pragma unroll
    for (int q = 0; q < 4; ++q) { v[q] = (i0 + q < N) ? hist[i0 + q] : 0; s += v[q]; }
    ts[t] = s;
    __syncthreads();
    // Hillis-Steele inclusive scan
    for (int off = 1; off < 256; off <<= 1) {
        int x = (t >= off) ? ts[t - off] : 0;
        __syncthreads();
        ts[t] += x;
        __syncthreads();
    }
    int run = partial[b] + ts[t] - s;   // exclusive base for this thread
    #pragma unroll
    for (int q = 0; q < 4; ++q) {
        int i = i0 + q;
        if (i < N) {
            nodeStart[i] = run;
            cursor[i] = run;
            if (i == N - 1) nodeStart[N] = run + v[q];
            run += v[q];
        }
    }
}

// ---------------- relation kernels ----------------
template <int D, bool SORTED>
__global__ __launch_bounds__(256) void rel_mfma(
    const u16* __restrict__ statesb, const int* __restrict__ idx,
    const u16* __restrict__ W1t, const float* __restrict__ B1,
    const u16* __restrict__ W2t, const float* __restrict__ B2,
    float* __restrict__ exps, unsigned* __restrict__ gmax,
    int* __restrict__ cursor, _Float16* __restrict__ msgbuf, int E) {
    constexpr int A = D / 64;
    constexpr int NF = D / 16;
    constexpr int KF = D / 32;
    __shared__ __align__(16) u16 Xs[64 * D];
    __shared__ int Ids[64 * A];
    char* Xc = (char*)Xs;

    const int tid = threadIdx.x;
    const int block0 = blockIdx.x * 64;
    const int validRows = min(64, E - block0);
    const int validSegs = validRows * A;
    const long long segBase = (long long)block0 * A;

    for (int q = tid; q < 64 * A * 8; q += 256) {
        int s = q >> 3, j = q & 7;
        int r = s / A, slot = s - r * A;
        bf16x8 v = {};
        if (s < validSegs) {
            int node = idx[segBase + s];
            v = *reinterpret_cast<const bf16x8*>(statesb + (long long)node * 64 + j * 8);
            if (j == 0) Ids[s] = node;
        }
        int byte = (slot * 128 + j * 16) ^ ((r & 7) << 4);
        *reinterpret_cast<bf16x8*>(Xc + r * (2 * D) + byte) = v;
    }
    __syncthreads();

    const int l = tid & 63;
    const int ln = l & 15, kq = l >> 4;
    const int row0 = (tid >> 6) * 16;

    f32x4 acc[NF];
    #pragma unroll
    for (int n = 0; n < NF; ++n) {
        float b = B1[n * 16 + ln];
        acc[n] = {b, b, b, b};
    }
    {
        const u16* wb = W1t + ln * D + kq * 8;
        #pragma unroll
        for (int kf = 0; kf < KF; ++kf) {
            bf16x8 a = *reinterpret_cast<const bf16x8*>(
                Xc + (row0 + ln) * (2 * D) + ((kf * 64 + kq * 16) ^ ((ln & 7) << 4)));
            #pragma unroll
            for (int n = 0; n < NF; ++n) {
                bf16x8 b = *reinterpret_cast<const bf16x8*>(wb + n * 16 * D + kf * 32);
                acc[n] = __builtin_amdgcn_mfma_f32_16x16x32_bf16(a, b, acc[n], 0, 0, 0);
            }
        }
    }
    #pragma unroll
    for (int n = 0; n < NF; ++n) {
        #pragma unroll
        for (int j = 0; j < 4; ++j) {
            int rl = kq * 4 + j;
            int byte = ((n * 16 + ln) * 2) ^ ((rl & 7) << 4);
            *reinterpret_cast<u16*>(Xc + (row0 + rl) * (2 * D) + byte) =
                f2bf(fmaxf(acc[n][j], 0.f));
        }
    }
    #pragma unroll
    for (int n = 0; n < NF; ++n) {
        float b = B2[n * 16 + ln];
        acc[n] = {b, b, b, b};
    }
    {
        const u16* wb = W2t + ln * D + kq * 8;
        #pragma unroll
        for (int kf = 0; kf < KF; ++kf) {
            bf16x8 a = *reinterpret_cast<const bf16x8*>(
                Xc + (row0 + ln) * (2 * D) + ((kf * 64 + kq * 16) ^ ((ln & 7) << 4)));
            #pragma unroll
            for (int n = 0; n < NF; ++n) {
                bf16x8 b = *reinterpret_cast<const bf16x8*>(wb + n * 16 * D + kf * 32);
                acc[n] = __builtin_amdgcn_mfma_f32_16x16x32_bf16(a, b, acc[n], 0, 0, 0);
            }
        }
    }

    // ---- epilogue
    float m = -INFINITY;
    #pragma unroll
    for (int n = 0; n < NF; ++n)
        #pragma unroll
        for (int j = 0; j < 4; ++j) {
            int row = row0 + kq * 4 + j;
            if (row < validRows) m = fmaxf(m, acc[n][j]);
        }
    #pragma unroll
    for (int off = 32; off; off >>= 1) m = fmaxf(m, __shfl_xor(m, off));
    if (l == 0) atomicMax(gmax, f2ord(m));

    if constexpr (SORTED) {
        #pragma unroll
        for (int j = 0; j < 4; ++j) {
            int row = row0 + kq * 4 + j;
            bool valid = row < validRows;
            int pos[A];
            #pragma unroll
            for (int s = 0; s < A; ++s) {
                int p = 0;
                if (ln == s && valid) {
                    int node = Ids[row * A + s];
                    p = atomicAdd(&cursor[node], 1);
                }
                pos[s] = __shfl(p, kq * 16 + s);
            }
            if (valid) {
                #pragma unroll
                for (int n = 0; n < NF; ++n) {
                    int slot = n >> 2;
                    int feat = (n & 3) * 16 + ln;
                    msgbuf[(long long)pos[slot] * 64 + feat] =
                        (_Float16)__expf(8.f * acc[n][j]);
                }
            }
        }
    } else {
        #pragma unroll
        for (int n = 0; n < NF; ++n) {
            const int slot = n >> 2;
            const int feat = (n * 16 + ln) & 63;
            #pragma unroll
            for (int j = 0; j < 4; ++j) {
                int row = row0 + kq * 4 + j;
                if (row < validRows) {
                    int node = Ids[row * A + slot];
                    atomicAdd(exps + (long long)node * 64 + feat, __expf(8.f * acc[n][j]));
                }
            }
        }
    }
}

// ---------------- segment reduce ----------------
__global__ __launch_bounds__(256) void reduce_k(const _Float16* __restrict__ msgbuf,
                                                const int* __restrict__ nodeStart,
                                                float* __restrict__ exps, int Nn) {
    int node = (blockIdx.x * 256 + threadIdx.x) >> 6;
    if (node >= Nn) return;
    int lane = threadIdx.x & 63;
    int s = nodeStart[node], e = nodeStart[node + 1];
    float S = 0.f;
    for (int i = s; i < e; ++i) S += (float)msgbuf[(long long)i * 64 + lane];
    exps[(long long)node * 64 + lane] = S;
}

// ---------------- up kernel ----------------
__global__ __launch_bounds__(256) void up_mfma(
    const u16* __restrict__ statesb, const float* __restrict__ exps,
    const unsigned* __restrict__ gmaxp,
    const u16* __restrict__ W1t, const float* __restrict__ B1,
    const u16* __restrict__ W2t, const float* __restrict__ B2,
    float* __restrict__ outp, int Nn) {
    constexpr int D = 128;
    __shared__ __align__(16) u16 Xs[64 * D];
    char* Xc = (char*)Xs;
    const int tid = threadIdx.x;
    const int block0 = blockIdx.x * 64;
    const int validRows = min(64, Nn - block0);
    const float M = ord2f(*gmaxp);
    const float EM = __expf(-8.f * M);

    for (int q = tid; q < 64 * 16; q += 256) {
        int r = q >> 4, p = q & 15;
        bf16x8 v = {};
        if (r < validRows) {
            long long nd = block0 + r;
            if (p < 8) {
                float4 s0 = *reinterpret_cast<const float4*>(exps + nd * 64 + p * 8);
                float4 s1 = *reinterpret_cast<const float4*>(exps + nd * 64 + p * 8 + 4);
                float t[8] = {s0.x, s0.y, s0.z, s0.w, s1.x, s1.y, s1.z, s1.w};
                #pragma unroll
                for (int i = 0; i < 8; ++i)
                    v[i] = (short)f2bf(__logf(1e-16f + t[i] * EM) * 0.125f + M);
            } else {
                v = *reinterpret_cast<const bf16x8*>(statesb + nd * 64 + (p - 8) * 8);
            }
        }
        int byte = (p * 16) ^ ((r & 7) << 4);
        *reinterpret_cast<bf16x8*>(Xc + r * 256 + byte) = v;
    }
    __syncthreads();

    const int l = tid & 63;
    const int ln = l & 15, kq = l >> 4;
    const int row0 = (tid >> 6) * 16;

    f32x4 acc[8];
    #pragma unroll
    for (int n = 0; n < 8; ++n) {
        float b = B1[n * 16 + ln];
        acc[n] = {b, b, b, b};
    }
    {
        const u16* wb = W1t + ln * D + kq * 8;
        #pragma unroll
        for (int kf = 0; kf < 4; ++kf) {
            bf16x8 a = *reinterpret_cast<const bf16x8*>(
                Xc + (row0 + ln) * 256 + ((kf * 64 + kq * 16) ^ ((ln & 7) << 4)));
            #pragma unroll
            for (int n = 0; n < 8; ++n) {
                bf16x8 b = *reinterpret_cast<const bf16x8*>(wb + n * 16 * D + kf * 32);
                acc[n] = __builtin_amdgcn_mfma_f32_16x16x32_bf16(a, b, acc[n], 0, 0, 0);
            }
        }
    }
    #pragma unroll
    for (int n = 0; n < 8; ++n) {
        #pragma unroll
        for (int j = 0; j < 4; ++j) {
            int rl = kq * 4 + j;
            int byte = ((n * 16 + ln) * 2) ^ ((rl & 7) << 4);
            *reinterpret_cast<u16*>(Xc + (row0 + rl) * 256 + byte) =
                f2bf(fmaxf(acc[n][j], 0.f));
        }
    }
    f32x4 acc2[4];
    #pragma unroll
    for (int n = 0; n < 4; ++n) {
        float b = B2[n * 16 + ln];
        acc2[n] = {b, b, b, b};
    }
    {
        const u16* wb = W2t + ln * D + kq * 8;
        #pragma unroll
        for (int kf = 0; kf < 4; ++kf) {
            bf16x8 a = *reinterpret_cast<const bf16x8*>(
                Xc + (row0 + ln) * 256 + ((kf * 64 + kq * 16) ^ ((ln & 7) << 4)));
            #pragma unroll
            for (int n = 0; n < 4; ++n) {
                bf16x8 b = *reinterpret_cast<const bf16x8*>(wb + n * 16 * D + kf * 32);
                acc2[n] = __builtin_amdgcn_mfma_f32_16x16x32_bf16(a, b, acc2[n], 0, 0, 0);
            }
        }
    }
    #pragma unroll
    for (int n = 0; n < 4; ++n)
        #pragma unroll
        for (int j = 0; j < 4; ++j) {
            int row = row0 + kq * 4 + j;
            if (row < validRows)
                outp[(long long)(block0 + row) * 64 + n * 16 + ln] = acc2[n][j];
        }
}

extern "C" void kernel_launch(void* const* d_in, const int* in_sizes, int n_in,
                              void* d_out, int out_size, void* d_ws, size_t ws_size,
                              hipStream_t stream) {
    const float* states = (const float*)d_in[0];
    const int* idxp[3] = {(const int*)d_in[1], (const int*)d_in[2], (const int*)d_in[3]};
    const float* rw1[3] = {(const float*)d_in[4], (const float*)d_in[8], (const float*)d_in[12]};
    const float* rb1[3] = {(const float*)d_in[5], (const float*)d_in[9], (const float*)d_in[13]};
    const float* rw2[3] = {(const float*)d_in[6], (const float*)d_in[10], (const float*)d_in[14]};
    const float* rb2[3] = {(const float*)d_in[7], (const float*)d_in[11], (const float*)d_in[15]};
    const float* upw1 = (const float*)d_in[16];
    const float* upb1 = (const float*)d_in[17];
    const float* upw2 = (const float*)d_in[18];
    const float* upb2 = (const float*)d_in[19];

    const int N = in_sizes[0] / 64;
    const int L0 = in_sizes[1], L1 = in_sizes[2], L2 = in_sizes[3];   // flat lengths
    const int E0 = L0 / 1, E1 = L1 / 2, E2 = L2 / 3;                  // tuple counts
    const int P = L0 + L1 + L2;                                       // total participants

    const int Dd[3] = {64, 128, 192};
    size_t wbytes = 0;
    for (int r = 0; r < 3; ++r) wbytes += 2 * (size_t)Dd[r] * Dd[r] * 2;
    wbytes += (128 * 128 + 64 * 128) * 2;

    // ---- try sorted layout
    size_t off = 0;
    auto alloc = [&](size_t bytes) {
        void* p = (char*)d_ws + off;
        off += (bytes + 255) & ~(size_t)255;
        return p;
    };
    unsigned* gmax = (unsigned*)alloc(4);              // offset 0
    int* hist = (int*)alloc((size_t)N * 4);            // memset with gmax
    int* nodeStart = (int*)alloc((size_t)(N + 1) * 4);
    int* partial = (int*)alloc(4096);
    int* cursor = (int*)alloc((size_t)N * 4);
    float* exps = (float*)alloc((size_t)N * 64 * 4);
    u16* statesb = (u16*)alloc((size_t)N * 64 * 2);
    u16* w1t[3], *w2t[3];
    for (int r = 0; r < 3; ++r) {
        w1t[r] = (u16*)alloc((size_t)Dd[r] * Dd[r] * 2);
        w2t[r] = (u16*)alloc((size_t)Dd[r] * Dd[r] * 2);
    }
    u16* upw1t = (u16*)alloc(128 * 128 * 2);
    u16* upw2t = (u16*)alloc(64 * 128 * 2);
    _Float16* msgbuf = (_Float16*)alloc((size_t)P * 64 * 2);
    const bool sorted = (off <= ws_size);

    TPack tp;
    const float* tsrc[8] = {rw1[0], rw2[0], rw1[1], rw2[1], rw1[2], rw2[2], upw1, upw2};
    const int tK[8] = {64, 64, 128, 128, 192, 192, 128, 128};
    const int tN[8] = {64, 64, 128, 128, 192, 192, 128, 64};

    if (sorted) {
        hipMemsetAsync(d_ws, 0, 256 + (size_t)N * 4, stream);  // gmax + hist
        conv_states<<<dim3((N * 64 / 8 + 255) / 256), dim3(256), 0, stream>>>(
            states, statesb, N * 64 / 8);
        u16* tdst[8] = {w1t[0], w2t[0], w1t[1], w2t[1], w1t[2], w2t[2], upw1t, upw2t};
        int base = 0;
        for (int i = 0; i < 8; ++i) {
            tp.e[i] = {tsrc[i], tdst[i], tK[i], tN[i], base};
            base += (tK[i] * tN[i] + 255) / 256;
        }
        transpose_w<<<dim3(base), dim3(256), 0, stream>>>(tp);

        hist_k<<<dim3((L0 + 255) / 256), dim3(256), 0, stream>>>(idxp[0], L0, hist);
        hist_k<<<dim3((L1 + 255) / 256), dim3(256), 0, stream>>>(idxp[1], L1, hist);
        hist_k<<<dim3((L2 + 255) / 256), dim3(256), 0, stream>>>(idxp[2], L2, hist);
        const int B1 = (N + 1023) / 1024;
        scanA<<<dim3(B1), dim3(256), 0, stream>>>(hist, N, partial);
        scanB<<<dim3(1), dim3(64), 0, stream>>>(partial, B1);
        scanC<<<dim3(B1), dim3(256), 0, stream>>>(hist, N, partial, nodeStart, cursor);

        rel_mfma<64, true><<<dim3((E0 + 63) / 64), dim3(256), 0, stream>>>(
            statesb, idxp[0], w1t[0], rb1[0], w2t[0], rb2[0], nullptr, gmax, cursor, msgbuf, E0);
        rel_mfma<128, true><<<dim3((E1 + 63) / 64), dim3(256), 0, stream>>>(
            statesb, idxp[1], w1t[1], rb1[1], w2t[1], rb2[1], nullptr, gmax, cursor, msgbuf, E1);
        rel_mfma<192, true><<<dim3((E2 + 63) / 64), dim3(256), 0, stream>>>(
            statesb, idxp[2], w1t[2], rb1[2], w2t[2], rb2[2], nullptr, gmax, cursor, msgbuf, E2);

        reduce_k<<<dim3((N * 64 + 255) / 256), dim3(256), 0, stream>>>(
            msgbuf, nodeStart, exps, N);
        up_mfma<<<dim3((N + 63) / 64), dim3(256), 0, stream>>>(
            statesb, exps, gmax, upw1t, upb1, upw2t, upb2, (float*)d_out, N);
    } else {
        // ---- fallback: round-3 atomic path (layout: gmax | exps | statesb | weights)
        off = 0;
        unsigned* g2 = (unsigned*)alloc(4);
        float* ex2 = (float*)alloc((size_t)N * 64 * 4);
        u16* sb2 = (u16*)alloc((size_t)N * 64 * 2);
        u16* fw1[3], *fw2[3];
        for (int r = 0; r < 3; ++r) {
            fw1[r] = (u16*)alloc((size_t)Dd[r] * Dd[r] * 2);
            fw2[r] = (u16*)alloc((size_t)Dd[r] * Dd[r] * 2);
        }
        u16* uw1 = (u16*)alloc(128 * 128 * 2);
        u16* uw2 = (u16*)alloc(64 * 128 * 2);
        hipMemsetAsync(d_ws, 0, 256 + (size_t)N * 64 * 4, stream);
        conv_states<<<dim3((N * 64 / 8 + 255) / 256), dim3(256), 0, stream>>>(
            states, sb2, N * 64 / 8);
        u16* tdst[8] = {fw1[0], fw2[0], fw1[1], fw2[1], fw1[2], fw2[2], uw1, uw2};
        int base = 0;
        for (int i = 0; i < 8; ++i) {
            tp.e[i] = {tsrc[i], tdst[i], tK[i], tN[i], base};
            base += (tK[i] * tN[i] + 255) / 256;
        }
        transpose_w<<<dim3(base), dim3(256), 0, stream>>>(tp);
        rel_mfma<64, false><<<dim3((E0 + 63) / 64), dim3(256), 0, stream>>>(
            sb2, idxp[0], fw1[0], rb1[0], fw2[0], rb2[0], ex2, g2, nullptr, nullptr, E0);
        rel_mfma<128, false><<<dim3((E1 + 63) / 64), dim3(256), 0, stream>>>(
            sb2, idxp[1], fw1[1], rb1[1], fw2[1], rb2[1], ex2, g2, nullptr, nullptr, E1);
        rel_mfma<192, false><<<dim3((E2 + 63) / 64), dim3(256), 0, stream>>>(
            sb2, idxp[2], fw1[2], rb1[2], fw2[2], rb2[2], ex2, g2, nullptr, nullptr, E2);
        up_mfma<<<dim3((N + 63) / 64), dim3(256), 0, stream>>>(
            sb2, ex2, g2, uw1, upb1, uw2, upb2, (float*)d_out, N);
    }
}